// Round 6
// baseline (833.487 us; speedup 1.0000x reference)
//
#include <hip/hip_runtime.h>
#include <stdint.h>

#define NN 100000
#define NE 1600000
#define FIN 602
#define KP1B 640     // 10 * 64, zero-padded K for layer-1 GEMM (BK=64)
#define H 256
#define C 42
#define NP2 48       // padded N for layer-2 GEMM (3 tiles of 16)
#define NB1 98       // ceil(NN / 1024) scan blocks

typedef __bf16 bf16;
typedef __bf16 bf16x8 __attribute__((ext_vector_type(8)));
typedef float f32x4 __attribute__((ext_vector_type(4)));

__device__ __forceinline__ float b2f(bf16 v) { return (float)v; }
__device__ __forceinline__ bf16 f2b(float v) { return (bf16)v; }
__device__ __forceinline__ float us2f(unsigned short u) {
    union { unsigned int i; float f; } w; w.i = ((unsigned int)u) << 16; return w.f;
}

// ---------------- CSR build ----------------

__global__ void k_zero(int* __restrict__ p, int n) {
    int i = blockIdx.x * 256 + threadIdx.x;
    if (i < n) p[i] = 0;
}

__global__ void k_count(const int* __restrict__ dst, int* __restrict__ cnt) {
    int e = blockIdx.x * 256 + threadIdx.x;
    if (e < NE) atomicAdd(&cnt[dst[e]], 1);
}

__global__ void k_dinv(const int* __restrict__ cnt, float* __restrict__ dinv) {
    int i = blockIdx.x * 256 + threadIdx.x;
    if (i < NN) dinv[i] = rsqrtf((float)(cnt[i] + 1));  // +1 self loop
}

__global__ __launch_bounds__(256) void k_scan1(const int* __restrict__ cnt,
                                               int* __restrict__ excl, int* __restrict__ bsum) {
    __shared__ int ts[256];
    const int tid = threadIdx.x;
    const int base = blockIdx.x * 1024 + tid * 4;
    int v[4];
#pragma unroll
    for (int j = 0; j < 4; ++j) v[j] = (base + j < NN) ? cnt[base + j] : 0;
    int s = v[0] + v[1] + v[2] + v[3];
    ts[tid] = s;
    __syncthreads();
    for (int off = 1; off < 256; off <<= 1) {
        int t = (tid >= off) ? ts[tid - off] : 0;
        __syncthreads();
        if (tid >= off) ts[tid] += t;
        __syncthreads();
    }
    int prefix = ts[tid] - s;
    if (tid == 255) bsum[blockIdx.x] = ts[255];
    int run = prefix;
#pragma unroll
    for (int j = 0; j < 4; ++j) {
        if (base + j < NN) excl[base + j] = run;
        run += v[j];
    }
}

__global__ __launch_bounds__(128) void k_scan2(int* __restrict__ bsum) {
    __shared__ int ts[128];
    const int tid = threadIdx.x;
    int v = (tid < NB1) ? bsum[tid] : 0;
    ts[tid] = v;
    __syncthreads();
    for (int off = 1; off < 128; off <<= 1) {
        int t = (tid >= off) ? ts[tid - off] : 0;
        __syncthreads();
        if (tid >= off) ts[tid] += t;
        __syncthreads();
    }
    if (tid < NB1) bsum[tid] = ts[tid] - v;
}

__global__ __launch_bounds__(256) void k_scan3(const int* __restrict__ excl, const int* __restrict__ bsum,
                                               int* __restrict__ rowptr, int* __restrict__ cursor) {
    const int tid = threadIdx.x;
    const int base = blockIdx.x * 1024 + tid * 4;
    const int add = bsum[blockIdx.x];
#pragma unroll
    for (int j = 0; j < 4; ++j) {
        int i = base + j;
        if (i < NN) { int r = excl[i] + add; rowptr[i] = r; cursor[i] = r; }
    }
    if (blockIdx.x == 0 && tid == 0) rowptr[NN] = NE;
}

__global__ void k_fill(const int* __restrict__ src, const int* __restrict__ dst,
                       int* __restrict__ cursor, int* __restrict__ esrc) {
    int e = blockIdx.x * 256 + threadIdx.x;
    if (e < NE) {
        int d = dst[e];
        int pos = atomicAdd(&cursor[d], 1);
        esrc[pos] = src[e];
    }
}

// ---------------- weight transposes + fp32->bf16 convert ----------------

// W1 fp32 [602][256] -> W1T bf16 [256][640] (zero-padded K to 640)
__global__ void k_transpose_w1(const float* __restrict__ w1, bf16* __restrict__ w1t) {
    int idx = blockIdx.x * 256 + threadIdx.x;  // grid covers 256*640 exactly
    int n = idx / KP1B;
    int k = idx % KP1B;
    w1t[idx] = (k < FIN) ? f2b(w1[(size_t)k * H + n]) : (bf16)0.0f;
}

__global__ void k_transpose_w2(const float* __restrict__ w2, bf16* __restrict__ w2t) {
    int idx = blockIdx.x * 256 + threadIdx.x;  // grid covers 48*256 exactly
    int n = idx >> 8;
    int k = idx & 255;
    w2t[idx] = (n < C) ? f2b(w2[(size_t)k * C + n]) : (bf16)0.0f;
}

// ---------------- GEMM1: h1[NN][256] = bf16(x)[NN][602] @ bf16(W1) ----------------
// 64-row tile, BK=64, LDS stride 72 (pad), register-prefetch double buffer.
// 4 waves; wave w covers cols [w*64,+64) (4 col-tiles) x 4 row-tiles = 32 MFMA/K-iter.

__global__ __launch_bounds__(256) void k_gemm1(const float* __restrict__ x,
                                               const bf16* __restrict__ w1t,
                                               bf16* __restrict__ h1) {
    __shared__ bf16 As[64 * 72];  // 9216 B
    const int tid = threadIdx.x;
    const int wave = tid >> 6;
    const int lane = tid & 63;
    const int q = lane >> 4;
    const int r = lane & 15;
    const int row0 = blockIdx.x * 64;

    // staging: thread t -> row (t>>2), 16-float segment (t&3)
    const int srow = tid >> 2;
    const int sseg = tid & 3;
    int gsrow = row0 + srow;
    if (gsrow >= NN) gsrow = NN - 1;  // clamp; stores guarded
    const float* xrow = x + (size_t)gsrow * FIN;

    float pf[16];
    auto load_chunk = [&](int kk) {
        const int c0 = kk * 64 + sseg * 16;
        if (c0 + 16 <= FIN) {
            const float2* p = (const float2*)(xrow + c0);  // 8B-aligned (row off mult of 8B)
#pragma unroll
            for (int jj = 0; jj < 8; ++jj) { float2 t = p[jj]; pf[2 * jj] = t.x; pf[2 * jj + 1] = t.y; }
        } else {
#pragma unroll
            for (int i = 0; i < 16; ++i) pf[i] = (c0 + i < FIN) ? xrow[c0 + i] : 0.f;
        }
    };
    load_chunk(0);

    f32x4 acc[4][4];  // [row-tile][col-tile]
#pragma unroll
    for (int a = 0; a < 4; ++a)
#pragma unroll
        for (int b = 0; b < 4; ++b) acc[a][b] = (f32x4){0.f, 0.f, 0.f, 0.f};

    const bf16* bbase = w1t + (size_t)(wave * 64) * KP1B;

    for (int kk = 0; kk < 10; ++kk) {
        union { bf16 s[16]; uint4 u[2]; } pk;
#pragma unroll
        for (int i = 0; i < 16; ++i) pk.s[i] = f2b(pf[i]);
        __syncthreads();  // prev-iter readers done
        uint4* ldst = (uint4*)(As + srow * 72 + sseg * 16);
        ldst[0] = pk.u[0];
        ldst[1] = pk.u[1];
        __syncthreads();  // writes visible
        if (kk < 9) load_chunk(kk + 1);  // prefetch in flight during compute

#pragma unroll
        for (int ks = 0; ks < 2; ++ks) {
            const int kb = ks * 32 + q * 8;
            bf16x8 af[4];
#pragma unroll
            for (int rt = 0; rt < 4; ++rt) {
                union { uint4 u; bf16x8 v; } ua;
                ua.u = *(const uint4*)(As + (rt * 16 + r) * 72 + kb);
                af[rt] = ua.v;
            }
#pragma unroll
            for (int ct = 0; ct < 4; ++ct) {
                const bf16* bp = bbase + (size_t)(ct * 16 + r) * KP1B + kk * 64 + kb;
                union { uint4 u; bf16x8 v; } ub;
                ub.u = *(const uint4*)bp;
#pragma unroll
                for (int rt = 0; rt < 4; ++rt)
                    acc[rt][ct] = __builtin_amdgcn_mfma_f32_16x16x32_bf16(af[rt], ub.v, acc[rt][ct], 0, 0, 0);
            }
        }
    }

#pragma unroll
    for (int rt = 0; rt < 4; ++rt) {
#pragma unroll
        for (int ct = 0; ct < 4; ++ct) {
            const int col = wave * 64 + ct * 16 + r;
#pragma unroll
            for (int rr = 0; rr < 4; ++rr) {
                const int m = row0 + rt * 16 + q * 4 + rr;
                if (m < NN) h1[(size_t)m * H + col] = f2b(acc[rt][ct][rr]);
            }
        }
    }
}

// ---------------- layer-1 pull aggregation + bias + relu (fused) ----------------
// one wave per node; 32-lane halves each handle one edge per load inst (uint4 =
// 16B/lane, 2 h1-rows per wave-instruction); unroll-4 -> 8 edges in flight.

__device__ __forceinline__ void acc8(float* a, uint4 v, float wgt) {
    a[0] += us2f((unsigned short)(v.x & 0xffff)) * wgt;
    a[1] += us2f((unsigned short)(v.x >> 16)) * wgt;
    a[2] += us2f((unsigned short)(v.y & 0xffff)) * wgt;
    a[3] += us2f((unsigned short)(v.y >> 16)) * wgt;
    a[4] += us2f((unsigned short)(v.z & 0xffff)) * wgt;
    a[5] += us2f((unsigned short)(v.z >> 16)) * wgt;
    a[6] += us2f((unsigned short)(v.w & 0xffff)) * wgt;
    a[7] += us2f((unsigned short)(v.w >> 16)) * wgt;
}

__global__ __launch_bounds__(64) void k_gather1(const int* __restrict__ rowptr,
                                                const int* __restrict__ esrc,
                                                const bf16* __restrict__ h1,
                                                const float* __restrict__ dinv,
                                                const float* __restrict__ b1,
                                                bf16* __restrict__ hb) {
    const int n = blockIdx.x;
    const int l = threadIdx.x;
    const int half = l >> 5;
    const int fl = l & 31;          // handles feats [fl*8, fl*8+8)
    const float dn = dinv[n];

    float a[8];
    {
        uint4 u = ((const uint4*)(h1 + (size_t)n * H))[fl];
        float ws = (half == 0) ? dn * dn : 0.f;   // self loop counted once
        a[0] = us2f((unsigned short)(u.x & 0xffff)) * ws;
        a[1] = us2f((unsigned short)(u.x >> 16)) * ws;
        a[2] = us2f((unsigned short)(u.y & 0xffff)) * ws;
        a[3] = us2f((unsigned short)(u.y >> 16)) * ws;
        a[4] = us2f((unsigned short)(u.z & 0xffff)) * ws;
        a[5] = us2f((unsigned short)(u.z >> 16)) * ws;
        a[6] = us2f((unsigned short)(u.w & 0xffff)) * ws;
        a[7] = us2f((unsigned short)(u.w >> 16)) * ws;
    }

    const int beg = rowptr[n], end = rowptr[n + 1];
    int j = beg;
    for (; j + 8 <= end; j += 8) {
        int s0 = esrc[j + half];
        int s1 = esrc[j + 2 + half];
        int s2 = esrc[j + 4 + half];
        int s3 = esrc[j + 6 + half];
        float w0 = dinv[s0] * dn, w1 = dinv[s1] * dn, w2 = dinv[s2] * dn, w3 = dinv[s3] * dn;
        uint4 v0 = ((const uint4*)(h1 + (size_t)s0 * H))[fl];
        uint4 v1 = ((const uint4*)(h1 + (size_t)s1 * H))[fl];
        uint4 v2 = ((const uint4*)(h1 + (size_t)s2 * H))[fl];
        uint4 v3 = ((const uint4*)(h1 + (size_t)s3 * H))[fl];
        acc8(a, v0, w0); acc8(a, v1, w1); acc8(a, v2, w2); acc8(a, v3, w3);
    }
    for (; j < end; j += 2) {
        int jj = j + half;
        if (jj < end) {
            int s = esrc[jj];
            float wgt = dinv[s] * dn;
            uint4 v = ((const uint4*)(h1 + (size_t)s * H))[fl];
            acc8(a, v, wgt);
        }
    }

    // combine halves
#pragma unroll
    for (int i = 0; i < 8; ++i) a[i] += __shfl_xor(a[i], 32, 64);

    if (half == 0) {
        float4 b0 = ((const float4*)b1)[fl * 2];
        float4 b4 = ((const float4*)b1)[fl * 2 + 1];
        a[0] += b0.x; a[1] += b0.y; a[2] += b0.z; a[3] += b0.w;
        a[4] += b4.x; a[5] += b4.y; a[6] += b4.z; a[7] += b4.w;
#pragma unroll
        for (int i = 0; i < 8; ++i) a[i] = a[i] > 0.f ? a[i] : 0.f;
        union { unsigned short s[8]; uint4 u; } pk;
        union { bf16 b; unsigned short s; } cv;
#pragma unroll
        for (int i = 0; i < 8; ++i) { cv.b = f2b(a[i]); pk.s[i] = cv.s; }
        ((uint4*)(hb + (size_t)n * H))[fl] = pk.u;
    }
}

// ---------------- GEMM2: h2[NN][42] = hb[NN][256] @ W2 ----------------
// 256-row tile, LDS stride 40 (pad), register-prefetch.

__global__ __launch_bounds__(256) void k_gemm2(const bf16* __restrict__ hb,
                                               const bf16* __restrict__ w2t,
                                               bf16* __restrict__ h2) {
    __shared__ bf16 As[256 * 40];  // 20480 B
    const int tid = threadIdx.x;
    const int wave = tid >> 6;
    const int lane = tid & 63;
    const int q = lane >> 4;
    const int r = lane & 15;
    const int row0 = blockIdx.x * 256;

    int gsrow = row0 + tid;
    if (gsrow >= NN) gsrow = NN - 1;
    const bf16* arow = hb + (size_t)gsrow * H;

    uint4 c[4];
    auto load_chunk = [&](int kk) {
        const bf16* p = arow + kk * 32;
        c[0] = *(const uint4*)(p);
        c[1] = *(const uint4*)(p + 8);
        c[2] = *(const uint4*)(p + 16);
        c[3] = *(const uint4*)(p + 24);
    };
    load_chunk(0);

    f32x4 acc[4][3];
#pragma unroll
    for (int a = 0; a < 4; ++a)
#pragma unroll
        for (int b = 0; b < 3; ++b) acc[a][b] = (f32x4){0.f, 0.f, 0.f, 0.f};

    for (int kk = 0; kk < 8; ++kk) {
        __syncthreads();
        uint4* ldst = (uint4*)(As + tid * 40);
        ldst[0] = c[0]; ldst[1] = c[1]; ldst[2] = c[2]; ldst[3] = c[3];
        __syncthreads();
        if (kk < 7) load_chunk(kk + 1);

        bf16x8 af[4];
#pragma unroll
        for (int rt = 0; rt < 4; ++rt) {
            union { uint4 u; bf16x8 v; } ua;
            ua.u = *(const uint4*)(As + (wave * 64 + rt * 16 + r) * 40 + q * 8);
            af[rt] = ua.v;
        }
#pragma unroll
        for (int ct = 0; ct < 3; ++ct) {
            const bf16* bp = w2t + (size_t)(ct * 16 + r) * H + kk * 32 + q * 8;
            union { uint4 u; bf16x8 v; } ub;
            ub.u = *(const uint4*)bp;
#pragma unroll
            for (int rt = 0; rt < 4; ++rt)
                acc[rt][ct] = __builtin_amdgcn_mfma_f32_16x16x32_bf16(af[rt], ub.v, acc[rt][ct], 0, 0, 0);
        }
    }

#pragma unroll
    for (int rt = 0; rt < 4; ++rt) {
#pragma unroll
        for (int ct = 0; ct < 3; ++ct) {
            const int col = ct * 16 + r;
            if (col < C) {
#pragma unroll
                for (int rr = 0; rr < 4; ++rr) {
                    const int m = row0 + wave * 64 + rt * 16 + q * 4 + rr;
                    if (m < NN) h2[(size_t)m * C + col] = f2b(acc[rt][ct][rr]);
                }
            }
        }
    }
}

// ---------------- layer-2 pull aggregation + bias + log_softmax (fused) ----------------

__global__ __launch_bounds__(64) void k_gather2(const int* __restrict__ rowptr,
                                                const int* __restrict__ esrc,
                                                const bf16* __restrict__ h2,
                                                const float* __restrict__ dinv,
                                                const float* __restrict__ b2,
                                                float* __restrict__ out) {
    const int n = blockIdx.x;
    const int cthread = threadIdx.x;
    const float dn = dinv[n];

    float acc = 0.f;
    if (cthread < C) acc = b2f(h2[(size_t)n * C + cthread]) * dn * dn;

    const int beg = rowptr[n], end = rowptr[n + 1];
    int j = beg;
    for (; j + 3 < end; j += 4) {
        int s0 = esrc[j], s1 = esrc[j + 1], s2 = esrc[j + 2], s3 = esrc[j + 3];
        float w0 = dinv[s0] * dn, w1 = dinv[s1] * dn, w2 = dinv[s2] * dn, w3 = dinv[s3] * dn;
        if (cthread < C) {
            float v0 = b2f(h2[(size_t)s0 * C + cthread]);
            float v1 = b2f(h2[(size_t)s1 * C + cthread]);
            float v2 = b2f(h2[(size_t)s2 * C + cthread]);
            float v3 = b2f(h2[(size_t)s3 * C + cthread]);
            acc += v0 * w0 + v1 * w1 + v2 * w2 + v3 * w3;
        }
    }
    for (; j < end; ++j) {
        int s = esrc[j];
        float wgt = dinv[s] * dn;
        if (cthread < C) acc += b2f(h2[(size_t)s * C + cthread]) * wgt;
    }

    float v = (cthread < C) ? acc + b2[cthread] : -INFINITY;
    float m = v;
#pragma unroll
    for (int o = 32; o > 0; o >>= 1) m = fmaxf(m, __shfl_xor(m, o, 64));
    float ex = (cthread < C) ? expf(v - m) : 0.f;
    float s = ex;
#pragma unroll
    for (int o = 32; o > 0; o >>= 1) s += __shfl_xor(s, o, 64);
    if (cthread < C) out[(size_t)n * C + cthread] = (v - m) - logf(s);
}

// ---------------- launch ----------------

extern "C" void kernel_launch(void* const* d_in, const int* in_sizes, int n_in,
                              void* d_out, int out_size, void* d_ws, size_t ws_size,
                              hipStream_t stream) {
    const float* x  = (const float*)d_in[0];  // fp32 [NN][602]
    const int*   ei = (const int*)d_in[1];    // int32 [2][NE]
    const float* w1 = (const float*)d_in[2];  // fp32 [602][256]
    const float* b1 = (const float*)d_in[3];  // fp32 [256]
    const float* w2 = (const float*)d_in[4];  // fp32 [256][42]
    const float* b2 = (const float*)d_in[5];  // fp32 [42]
    float* out = (float*)d_out;               // fp32 [NN][42]

    const int* src = ei;
    const int* dst = ei + NE;

    char* base = (char*)d_ws;
    size_t off = 0;
    auto alloc = [&](size_t bytes) -> void* {
        void* p = base + off;
        off += (bytes + 255) & ~(size_t)255;
        return p;
    };
    int*   cnt    = (int*)alloc((size_t)NN * 4);
    float* dinv   = (float*)alloc((size_t)NN * 4);
    int*   excl   = (int*)alloc((size_t)NN * 4);
    int*   bsum   = (int*)alloc(128 * 4);
    int*   rowptr = (int*)alloc((size_t)(NN + 1) * 4);
    int*   cursor = (int*)alloc((size_t)NN * 4);
    int*   esrc   = (int*)alloc((size_t)NE * 4);
    bf16*  w1t    = (bf16*)alloc((size_t)H * KP1B * 2);
    bf16*  w2t    = (bf16*)alloc((size_t)NP2 * H * 2);
    bf16*  h1     = (bf16*)alloc((size_t)NN * H * 2);
    bf16*  hb     = (bf16*)alloc((size_t)NN * H * 2);
    bf16*  h2     = (bf16*)alloc((size_t)NN * C * 2);
    (void)ws_size;

    // CSR build + norm
    k_zero<<<dim3((NN + 255) / 256), dim3(256), 0, stream>>>(cnt, NN);
    k_count<<<dim3((NE + 255) / 256), dim3(256), 0, stream>>>(dst, cnt);
    k_dinv<<<dim3((NN + 255) / 256), dim3(256), 0, stream>>>(cnt, dinv);
    k_scan1<<<dim3(NB1), dim3(256), 0, stream>>>(cnt, excl, bsum);
    k_scan2<<<dim3(1), dim3(128), 0, stream>>>(bsum);
    k_scan3<<<dim3(NB1), dim3(256), 0, stream>>>(excl, bsum, rowptr, cursor);
    k_fill<<<dim3((NE + 255) / 256), dim3(256), 0, stream>>>(src, dst, cursor, esrc);

    // weights
    k_transpose_w1<<<dim3(KP1B), dim3(256), 0, stream>>>(w1, w1t);  // 256*640 elems
    k_transpose_w2<<<dim3(NP2), dim3(256), 0, stream>>>(w2, w2t);

    // layer 1
    k_gemm1<<<dim3((NN + 63) / 64), dim3(256), 0, stream>>>(x, w1t, h1);
    k_gather1<<<dim3(NN), dim3(64), 0, stream>>>(rowptr, esrc, h1, dinv, b1, hb);

    // layer 2
    k_gemm2<<<dim3((NN + 255) / 256), dim3(256), 0, stream>>>(hb, w2t, h2);
    k_gather2<<<dim3(NN), dim3(64), 0, stream>>>(rowptr, esrc, h2, dinv, b2, out);
}